// Round 1
// baseline (3535.949 us; speedup 1.0000x reference)
//
#include <hip/hip_runtime.h>
#include <stdint.h>
#include <stddef.h>

#define B_   16
#define T_   256
#define L_   1024
#define H_   1024
#define G3_  3072
#define KIN_ 96

typedef __attribute__((ext_vector_type(8))) __bf16 bf16x8;
typedef __attribute__((ext_vector_type(4))) float  f32x4;
typedef __attribute__((ext_vector_type(4))) int    i32x4;

static __device__ __forceinline__ unsigned short f2bf(float x) {
  unsigned int u = __builtin_bit_cast(unsigned int, x);
  u += 0x7FFFu + ((u >> 16) & 1u);           // RNE
  return (unsigned short)(u >> 16);
}
static __device__ __forceinline__ float bf2f(unsigned short s) {
  unsigned int u = ((unsigned int)s) << 16;
  return __builtin_bit_cast(float, u);
}

// ---------------------------------------------------------------- converts
__global__ void cvt_bf16_kernel(const float* __restrict__ in,
                                unsigned short* __restrict__ out, int n) {
  int i = blockIdx.x * 256 + threadIdx.x;
  int stride = gridDim.x * 256;
  for (; i < n; i += stride) out[i] = f2bf(in[i]);
}

__global__ void transpose_bf16_kernel(const float* __restrict__ in,
                                      unsigned short* __restrict__ out,
                                      int R, int C) {
  int i = blockIdx.x * 256 + threadIdx.x;
  int n = R * C, stride = gridDim.x * 256;
  for (; i < n; i += stride) {
    int r = i / C, c = i % C;
    out[(size_t)c * R + r] = f2bf(in[i]);
  }
}

__global__ void ones_kernel(float* __restrict__ p, int n) {
  int i = blockIdx.x * 256 + threadIdx.x;
  if (i < n) p[i] = 1.0f;
}

// ---------------------------------------------------------------- conv+pool
// One block per (b,t) row. relu(max_p(conv)+bias) == max_p(relu(conv+bias)).
__global__ __launch_bounds__(256) void conv_kernel(
    const float* __restrict__ x,
    const float* __restrict__ w3, const float* __restrict__ b3,
    const float* __restrict__ w5, const float* __restrict__ b5,
    const float* __restrict__ w7, const float* __restrict__ b7,
    unsigned short* __restrict__ feat) {
  __shared__ float xpad[L_ + 8];
  __shared__ float wlds[96][8];
  __shared__ float blds[96];
  __shared__ float wmax[4][96];
  const int tid = threadIdx.x;
  const int rid = blockIdx.x;          // b*T + t
  const int b = rid >> 8;
  const int t = rid & 255;
  const float* xr = x + (size_t)rid * L_;
  for (int off = tid; off < L_; off += 256) xpad[off + 3] = xr[off];
  if (tid < 3) xpad[tid] = 0.f;
  if (tid >= 3 && tid < 8) xpad[L_ + tid] = 0.f;   // 1027..1031
  if (tid < 96) {
    const int f = tid;
    float wv[8];
#pragma unroll
    for (int k = 0; k < 8; ++k) wv[k] = 0.f;
    float bv;
    if (f < 32)      { for (int k = 0; k < 3; ++k) wv[k + 2] = w3[f * 3 + k]; bv = b3[f]; }
    else if (f < 64) { int ff = f - 32; for (int k = 0; k < 5; ++k) wv[k + 1] = w5[ff * 5 + k]; bv = b5[ff]; }
    else             { int ff = f - 64; for (int k = 0; k < 7; ++k) wv[k] = w7[ff * 7 + k]; bv = b7[ff]; }
#pragma unroll
    for (int k = 0; k < 8; ++k) wlds[f][k] = wv[k];
    blds[f] = bv;
  }
  __syncthreads();
  const int w = tid >> 6, lane = tid & 63;
  const int p0 = w * 256 + lane * 4;     // 4 consecutive positions per lane
  float xv[10];
#pragma unroll
  for (int i = 0; i < 10; ++i) xv[i] = xpad[p0 + i];
  for (int f = 0; f < 96; ++f) {
    float a0 = 0.f, a1 = 0.f, a2 = 0.f, a3 = 0.f;
#pragma unroll
    for (int k = 0; k < 7; ++k) {
      const float wk = wlds[f][k];
      a0 = fmaf(wk, xv[k],     a0);
      a1 = fmaf(wk, xv[k + 1], a1);
      a2 = fmaf(wk, xv[k + 2], a2);
      a3 = fmaf(wk, xv[k + 3], a3);
    }
    float m = fmaxf(fmaxf(a0, a1), fmaxf(a2, a3));
#pragma unroll
    for (int d = 1; d < 64; d <<= 1) m = fmaxf(m, __shfl_xor(m, d, 64));
    if (lane == 0) wmax[w][f] = m;
  }
  __syncthreads();
  if (tid < 96) {
    float m = fmaxf(fmaxf(wmax[0][tid], wmax[1][tid]),
                    fmaxf(wmax[2][tid], wmax[3][tid]));
    m += blds[tid];
    m = m > 0.f ? m : 0.f;
    feat[(size_t)(t * B_ + b) * KIN_ + tid] = f2bf(m);   // row = t*B + b
  }
}

// ---------------------------------------------------------------- GEMM
// C[M,N] = A[M,K] * B[N,K]^T  (both bf16, row-major, ld = K-stride).
// 128x128 tile, BK=32, 4 waves (each 32 rows x 128 cols), double-buffered LDS,
// padded stride 40 elems (80B) to keep ds_read_b128 conflicts <=4-way.
// EP: 0 = +bias -> f32 (gates); 1 = inhib = bf2f(A[row,col]) - relu(acc) -> bf16;
//     2 = relu(acc+bias) -> bf16; 3 = acc+bias -> d_out[(b*T+t)*H + col].
template <int EP>
__global__ __launch_bounds__(256) void gemm_kernel(
    const unsigned short* __restrict__ A,
    const unsigned short* __restrict__ Bm,
    int M, int N, int K, int lda, int ldb,
    const float* __restrict__ bias,
    float* __restrict__ outF,
    unsigned short* __restrict__ outB) {
  __shared__ __align__(16) unsigned short As[2][128 * 40];
  __shared__ __align__(16) unsigned short Bs[2][128 * 40];
  const int tid = threadIdx.x;
  const int n0 = blockIdx.x * 128;
  const int m0 = blockIdx.y * 128;
  const int w = tid >> 6;
  const int l = tid & 63;
  const int lr = l & 15;
  const int lk = (l >> 4) * 8;
  const int srow = tid >> 2;
  const int skc = (tid & 3) * 8;

  f32x4 acc[2][8];
#pragma unroll
  for (int i = 0; i < 2; ++i)
#pragma unroll
    for (int j = 0; j < 8; ++j) acc[i][j] = (f32x4){0.f, 0.f, 0.f, 0.f};

  const int NK = K >> 5;
  const unsigned short* Aptr  = A  + (size_t)(m0 + srow)      * lda + skc;
  const unsigned short* Aptr2 = A  + (size_t)(m0 + 64 + srow) * lda + skc;
  const unsigned short* Bptr  = Bm + (size_t)(n0 + srow)      * ldb + skc;
  const unsigned short* Bptr2 = Bm + (size_t)(n0 + 64 + srow) * ldb + skc;

  i32x4 ar0 = *(const i32x4*)(Aptr);
  i32x4 ar1 = *(const i32x4*)(Aptr2);
  i32x4 br0 = *(const i32x4*)(Bptr);
  i32x4 br1 = *(const i32x4*)(Bptr2);
  *(i32x4*)&As[0][srow * 40 + skc]        = ar0;
  *(i32x4*)&As[0][(64 + srow) * 40 + skc] = ar1;
  *(i32x4*)&Bs[0][srow * 40 + skc]        = br0;
  *(i32x4*)&Bs[0][(64 + srow) * 40 + skc] = br1;
  __syncthreads();

  for (int kk = 0; kk < NK; ++kk) {
    const int cur = kk & 1;
    if (kk + 1 < NK) {
      const int ko = (kk + 1) << 5;
      ar0 = *(const i32x4*)(Aptr  + ko);
      ar1 = *(const i32x4*)(Aptr2 + ko);
      br0 = *(const i32x4*)(Bptr  + ko);
      br1 = *(const i32x4*)(Bptr2 + ko);
    }
    const bf16x8 a0 = *(const bf16x8*)&As[cur][(w * 32 + lr) * 40 + lk];
    const bf16x8 a1 = *(const bf16x8*)&As[cur][(w * 32 + 16 + lr) * 40 + lk];
#pragma unroll
    for (int nt = 0; nt < 8; ++nt) {
      const bf16x8 bb = *(const bf16x8*)&Bs[cur][(nt * 16 + lr) * 40 + lk];
      acc[0][nt] = __builtin_amdgcn_mfma_f32_16x16x32_bf16(a0, bb, acc[0][nt], 0, 0, 0);
      acc[1][nt] = __builtin_amdgcn_mfma_f32_16x16x32_bf16(a1, bb, acc[1][nt], 0, 0, 0);
    }
    __syncthreads();
    if (kk + 1 < NK) {
      const int nxt = cur ^ 1;
      *(i32x4*)&As[nxt][srow * 40 + skc]        = ar0;
      *(i32x4*)&As[nxt][(64 + srow) * 40 + skc] = ar1;
      *(i32x4*)&Bs[nxt][srow * 40 + skc]        = br0;
      *(i32x4*)&Bs[nxt][(64 + srow) * 40 + skc] = br1;
    }
    __syncthreads();
  }

#pragma unroll
  for (int mt = 0; mt < 2; ++mt) {
#pragma unroll
    for (int nt = 0; nt < 8; ++nt) {
      const f32x4 v = acc[mt][nt];
      const int gcol = n0 + nt * 16 + lr;
#pragma unroll
      for (int e = 0; e < 4; ++e) {
        const int grow = m0 + w * 32 + mt * 16 + (l >> 4) * 4 + e;
        const float val = v[e];
        if (EP == 0) {
          outF[(size_t)grow * N + gcol] = val + bias[gcol];
        } else if (EP == 1) {
          const float hsv = bf2f(A[(size_t)grow * lda + gcol]);
          outB[(size_t)grow * N + gcol] = f2bf(hsv - fmaxf(val, 0.f));
        } else if (EP == 2) {
          outB[(size_t)grow * N + gcol] = f2bf(fmaxf(val + bias[gcol], 0.f));
        } else {
          const int tt = grow >> 4;   // row = t*B + b
          const int bb2 = grow & 15;
          outF[((size_t)bb2 * T_ + tt) * H_ + gcol] = val + bias[gcol];
        }
      }
    }
  }
}

// ---------------------------------------------------------------- GRU scan
// Persistent dataflow kernel: 64 WGs x 256 thr. WG g owns H-cols [16g,16g+16)
// => W_hh rows {j, 1024+j, 2048+j}. A-fragments preloaded to registers once.
// h exchanged through hs (bf16, slice t) + per-step device-scope counter.
__global__ __launch_bounds__(256) void gru_scan_kernel(
    const unsigned short* __restrict__ Whh,   // [3072][1024] bf16
    const float* __restrict__ gates,          // [T*B][3072] (= x-gates + b_ih)
    const float* __restrict__ bhh,            // [3072]
    unsigned short* __restrict__ hs,          // [T+1][B][H] bf16; slice0 = 0
    int* __restrict__ cnt) {                  // [T+1], zeroed
  __shared__ __align__(16) float ghp[4][3][16][16];   // [wave][gate][batch][j]
  const int tid = threadIdx.x;
  const int g = blockIdx.x;
  const int w = tid >> 6;
  const int l = tid & 63;
  const int lr = l & 15;
  const int lk8 = (l >> 4) * 8;
  const int j0 = g * 16;

  // Preload A fragments: wave w covers K range [256w, 256w+256)
  bf16x8 af[3][8];
#pragma unroll
  for (int m = 0; m < 3; ++m) {
    const size_t row = (size_t)(m * H_ + j0 + lr);
#pragma unroll
    for (int kk = 0; kk < 8; ++kk) {
      const int k = w * 256 + kk * 32 + lk8;
      af[m][kk] = *(const bf16x8*)(Whh + row * H_ + k);
    }
  }
  const int jb = tid & 15;   // j within chunk
  const int bb = tid >> 4;   // batch
  const float bhr = bhh[j0 + jb];
  const float bhz = bhh[H_ + j0 + jb];
  const float bhn = bhh[2 * H_ + j0 + jb];
  float hprev = 0.f;

  for (int t = 0; t < T_; ++t) {
    // prefetch x-gates early (independent of h) to hide HBM latency
    const size_t grow = ((size_t)t * B_ + bb) * G3_;
    const float gxr = gates[grow + j0 + jb];
    const float gxz = gates[grow + H_ + j0 + jb];
    const float gxn = gates[grow + 2 * H_ + j0 + jb];

    if (t > 0) {
      if (tid == 0) {
        while (__hip_atomic_load(cnt + t, __ATOMIC_ACQUIRE,
                                 __HIP_MEMORY_SCOPE_AGENT) < 64) {
          __builtin_amdgcn_s_sleep(2);
        }
      }
      __syncthreads();
      __threadfence();   // invalidate stale lines before reading remote h
    }

    f32x4 C0 = (f32x4){0.f, 0.f, 0.f, 0.f}, C1 = C0, C2 = C0;
    const unsigned short* hb = hs + (size_t)t * (B_ * H_) + (size_t)lr * H_;
#pragma unroll
    for (int kk = 0; kk < 8; ++kk) {
      const int k = w * 256 + kk * 32 + lk8;
      const bf16x8 bf = *(const bf16x8*)(hb + k);
      C0 = __builtin_amdgcn_mfma_f32_16x16x32_bf16(af[0][kk], bf, C0, 0, 0, 0);
      C1 = __builtin_amdgcn_mfma_f32_16x16x32_bf16(af[1][kk], bf, C1, 0, 0, 0);
      C2 = __builtin_amdgcn_mfma_f32_16x16x32_bf16(af[2][kk], bf, C2, 0, 0, 0);
    }
    const int rbase = (l >> 4) * 4;
    *(f32x4*)&ghp[w][0][lr][rbase] = C0;
    *(f32x4*)&ghp[w][1][lr][rbase] = C1;
    *(f32x4*)&ghp[w][2][lr][rbase] = C2;
    __syncthreads();

    const float ghr = ghp[0][0][bb][jb] + ghp[1][0][bb][jb] +
                      ghp[2][0][bb][jb] + ghp[3][0][bb][jb] + bhr;
    const float ghz = ghp[0][1][bb][jb] + ghp[1][1][bb][jb] +
                      ghp[2][1][bb][jb] + ghp[3][1][bb][jb] + bhz;
    const float ghn = ghp[0][2][bb][jb] + ghp[1][2][bb][jb] +
                      ghp[2][2][bb][jb] + ghp[3][2][bb][jb] + bhn;
    const float r = 1.f / (1.f + __expf(-(gxr + ghr)));
    const float z = 1.f / (1.f + __expf(-(gxz + ghz)));
    const float xn = gxn + r * ghn;
    const float n = 2.f / (1.f + __expf(-2.f * xn)) - 1.f;
    const float hnew = (1.f - z) * n + z * hprev;   // carry stays fp32
    hprev = hnew;
    hs[((size_t)(t + 1) * B_ + bb) * H_ + j0 + jb] = f2bf(hnew);
    __threadfence();      // make our chunk agent-visible
    __syncthreads();      // also guards ghp reuse next step
    if (tid == 0) {
      __hip_atomic_fetch_add(cnt + t + 1, 1, __ATOMIC_RELEASE,
                             __HIP_MEMORY_SCOPE_AGENT);
    }
  }
}

// ---------------------------------------------------------------- launch
extern "C" void kernel_launch(void* const* d_in, const int* in_sizes, int n_in,
                              void* d_out, int out_size, void* d_ws, size_t ws_size,
                              hipStream_t stream) {
  (void)in_sizes; (void)n_in; (void)out_size; (void)ws_size;
  const float* x    = (const float*)d_in[0];
  const float* w3   = (const float*)d_in[1];
  const float* b3   = (const float*)d_in[2];
  const float* w5   = (const float*)d_in[3];
  const float* b5   = (const float*)d_in[4];
  const float* w7   = (const float*)d_in[5];
  const float* b7   = (const float*)d_in[6];
  const float* wih  = (const float*)d_in[7];
  const float* whh  = (const float*)d_in[8];
  const float* bih  = (const float*)d_in[9];
  const float* bhh  = (const float*)d_in[10];
  // d_in[11..14]: attn_* — dead code (softmax over length-1 axis == 1)
  const float* fiw1 = (const float*)d_in[15];
  const float* fib1 = (const float*)d_in[16];
  const float* fiw2 = (const float*)d_in[17];
  const float* fib2 = (const float*)d_in[18];
  const float* lat  = (const float*)d_in[19];

  char* ws = (char*)d_ws;
  size_t off = 0;
  auto alloc = [&](size_t bytes) -> void* {
    void* p = ws + off;
    off += (bytes + 255) & ~(size_t)255;
    return p;
  };
  unsigned short* whh_bf  = (unsigned short*)alloc((size_t)G3_ * H_ * 2);
  unsigned short* wih_bf  = (unsigned short*)alloc((size_t)G3_ * KIN_ * 2);
  unsigned short* latT_bf = (unsigned short*)alloc((size_t)H_ * H_ * 2);
  unsigned short* fiw1_bf = (unsigned short*)alloc((size_t)H_ * H_ * 2);
  unsigned short* fiw2_bf = (unsigned short*)alloc((size_t)H_ * H_ * 2);
  unsigned short* feat_bf = (unsigned short*)alloc((size_t)B_ * T_ * KIN_ * 2);
  float*          gates   = (float*)alloc((size_t)B_ * T_ * G3_ * 4);
  unsigned short* hsbuf   = (unsigned short*)alloc((size_t)(T_ + 1) * B_ * H_ * 2);
  unsigned short* inhib   = (unsigned short*)alloc((size_t)B_ * T_ * H_ * 2);
  unsigned short* y1      = (unsigned short*)alloc((size_t)B_ * T_ * H_ * 2);
  int*            cnt     = (int*)alloc((size_t)(T_ + 2) * 4);

  hipMemsetAsync(cnt, 0, (T_ + 2) * 4, stream);
  hipMemsetAsync(hsbuf, 0, (size_t)B_ * H_ * 2, stream);   // h0 = 0

  cvt_bf16_kernel<<<2048, 256, 0, stream>>>(whh, whh_bf, G3_ * H_);
  cvt_bf16_kernel<<<1024, 256, 0, stream>>>(wih, wih_bf, G3_ * KIN_);
  cvt_bf16_kernel<<<1024, 256, 0, stream>>>(fiw1, fiw1_bf, H_ * H_);
  cvt_bf16_kernel<<<1024, 256, 0, stream>>>(fiw2, fiw2_bf, H_ * H_);
  transpose_bf16_kernel<<<1024, 256, 0, stream>>>(lat, latT_bf, H_, H_);

  conv_kernel<<<B_ * T_, 256, 0, stream>>>(x, w3, b3, w5, b5, w7, b7, feat_bf);

  {
    dim3 grid(G3_ / 128, (B_ * T_) / 128);
    gemm_kernel<0><<<grid, 256, 0, stream>>>(feat_bf, wih_bf, B_ * T_, G3_, KIN_,
                                             KIN_, KIN_, bih, gates, nullptr);
  }

  gru_scan_kernel<<<64, 256, 0, stream>>>(whh_bf, gates, bhh, hsbuf, cnt);

  const unsigned short* hs1 = hsbuf + (size_t)B_ * H_;   // slices 1..T
  {
    dim3 grid(H_ / 128, (B_ * T_) / 128);
    gemm_kernel<1><<<grid, 256, 0, stream>>>(hs1, latT_bf, B_ * T_, H_, H_,
                                             H_, H_, nullptr, nullptr, inhib);
    gemm_kernel<2><<<grid, 256, 0, stream>>>(inhib, fiw1_bf, B_ * T_, H_, H_,
                                             H_, H_, fib1, nullptr, y1);
    gemm_kernel<3><<<grid, 256, 0, stream>>>(y1, fiw2_bf, B_ * T_, H_, H_,
                                             H_, H_, fib2, (float*)d_out, nullptr);
  }

  ones_kernel<<<16, 256, 0, stream>>>((float*)d_out + (size_t)B_ * T_ * H_, B_ * T_);
}

// Round 2
// 1141.280 us; speedup vs baseline: 3.0982x; 3.0982x over previous
//
#include <hip/hip_runtime.h>
#include <stdint.h>
#include <stddef.h>

#define B_   16
#define T_   256
#define L_   1024
#define H_   1024
#define G3_  3072
#define KIN_ 96

typedef __attribute__((ext_vector_type(8))) __bf16 bf16x8;
typedef __attribute__((ext_vector_type(4))) float  f32x4;
typedef __attribute__((ext_vector_type(4))) int    i32x4;

static __device__ __forceinline__ unsigned short f2bf(float x) {
  unsigned int u = __builtin_bit_cast(unsigned int, x);
  u += 0x7FFFu + ((u >> 16) & 1u);           // RNE
  return (unsigned short)(u >> 16);
}
static __device__ __forceinline__ float bf2f(unsigned short s) {
  unsigned int u = ((unsigned int)s) << 16;
  return __builtin_bit_cast(float, u);
}

// ---------------------------------------------------------------- converts
__global__ void cvt_bf16_kernel(const float* __restrict__ in,
                                unsigned short* __restrict__ out, int n) {
  int i = blockIdx.x * 256 + threadIdx.x;
  int stride = gridDim.x * 256;
  for (; i < n; i += stride) out[i] = f2bf(in[i]);
}

__global__ void transpose_bf16_kernel(const float* __restrict__ in,
                                      unsigned short* __restrict__ out,
                                      int R, int C) {
  int i = blockIdx.x * 256 + threadIdx.x;
  int n = R * C, stride = gridDim.x * 256;
  for (; i < n; i += stride) {
    int r = i / C, c = i % C;
    out[(size_t)c * R + r] = f2bf(in[i]);
  }
}

__global__ void ones_kernel(float* __restrict__ p, int n) {
  int i = blockIdx.x * 256 + threadIdx.x;
  if (i < n) p[i] = 1.0f;
}

// ---------------------------------------------------------------- conv+pool
// One block per (b,t) row. relu(max_p(conv)+bias) == max_p(relu(conv+bias)).
__global__ __launch_bounds__(256) void conv_kernel(
    const float* __restrict__ x,
    const float* __restrict__ w3, const float* __restrict__ b3,
    const float* __restrict__ w5, const float* __restrict__ b5,
    const float* __restrict__ w7, const float* __restrict__ b7,
    unsigned short* __restrict__ feat) {
  __shared__ float xpad[L_ + 8];
  __shared__ float wlds[96][8];
  __shared__ float blds[96];
  __shared__ float wmax[4][96];
  const int tid = threadIdx.x;
  const int rid = blockIdx.x;          // b*T + t
  const int b = rid >> 8;
  const int t = rid & 255;
  const float* xr = x + (size_t)rid * L_;
  for (int off = tid; off < L_; off += 256) xpad[off + 3] = xr[off];
  if (tid < 3) xpad[tid] = 0.f;
  if (tid >= 3 && tid < 8) xpad[L_ + tid] = 0.f;   // 1027..1031
  if (tid < 96) {
    const int f = tid;
    float wv[8];
#pragma unroll
    for (int k = 0; k < 8; ++k) wv[k] = 0.f;
    float bv;
    if (f < 32)      { for (int k = 0; k < 3; ++k) wv[k + 2] = w3[f * 3 + k]; bv = b3[f]; }
    else if (f < 64) { int ff = f - 32; for (int k = 0; k < 5; ++k) wv[k + 1] = w5[ff * 5 + k]; bv = b5[ff]; }
    else             { int ff = f - 64; for (int k = 0; k < 7; ++k) wv[k] = w7[ff * 7 + k]; bv = b7[ff]; }
#pragma unroll
    for (int k = 0; k < 8; ++k) wlds[f][k] = wv[k];
    blds[f] = bv;
  }
  __syncthreads();
  const int w = tid >> 6, lane = tid & 63;
  const int p0 = w * 256 + lane * 4;     // 4 consecutive positions per lane
  float xv[10];
#pragma unroll
  for (int i = 0; i < 10; ++i) xv[i] = xpad[p0 + i];
  for (int f = 0; f < 96; ++f) {
    float a0 = 0.f, a1 = 0.f, a2 = 0.f, a3 = 0.f;
#pragma unroll
    for (int k = 0; k < 7; ++k) {
      const float wk = wlds[f][k];
      a0 = fmaf(wk, xv[k],     a0);
      a1 = fmaf(wk, xv[k + 1], a1);
      a2 = fmaf(wk, xv[k + 2], a2);
      a3 = fmaf(wk, xv[k + 3], a3);
    }
    float m = fmaxf(fmaxf(a0, a1), fmaxf(a2, a3));
#pragma unroll
    for (int d = 1; d < 64; d <<= 1) m = fmaxf(m, __shfl_xor(m, d, 64));
    if (lane == 0) wmax[w][f] = m;
  }
  __syncthreads();
  if (tid < 96) {
    float m = fmaxf(fmaxf(wmax[0][tid], wmax[1][tid]),
                    fmaxf(wmax[2][tid], wmax[3][tid]));
    m += blds[tid];
    m = m > 0.f ? m : 0.f;
    feat[(size_t)(t * B_ + b) * KIN_ + tid] = f2bf(m);   // row = t*B + b
  }
}

// ---------------------------------------------------------------- GEMM
// C[M,N] = A[M,K] * B[N,K]^T  (both bf16, row-major, ld = K-stride).
// 128x128 tile, BK=32, 4 waves, double-buffered LDS, padded stride 40.
// EP: 0 = +bias -> f32 (gates); 1 = inhib = bf2f(A[row,col]) - relu(acc) -> bf16;
//     2 = relu(acc+bias) -> bf16; 3 = acc+bias -> d_out[(b*T+t)*H + col].
template <int EP>
__global__ __launch_bounds__(256) void gemm_kernel(
    const unsigned short* __restrict__ A,
    const unsigned short* __restrict__ Bm,
    int M, int N, int K, int lda, int ldb,
    const float* __restrict__ bias,
    float* __restrict__ outF,
    unsigned short* __restrict__ outB) {
  __shared__ __align__(16) unsigned short As[2][128 * 40];
  __shared__ __align__(16) unsigned short Bs[2][128 * 40];
  const int tid = threadIdx.x;
  const int n0 = blockIdx.x * 128;
  const int m0 = blockIdx.y * 128;
  const int w = tid >> 6;
  const int l = tid & 63;
  const int lr = l & 15;
  const int lk = (l >> 4) * 8;
  const int srow = tid >> 2;
  const int skc = (tid & 3) * 8;

  f32x4 acc[2][8];
#pragma unroll
  for (int i = 0; i < 2; ++i)
#pragma unroll
    for (int j = 0; j < 8; ++j) acc[i][j] = (f32x4){0.f, 0.f, 0.f, 0.f};

  const int NK = K >> 5;
  const unsigned short* Aptr  = A  + (size_t)(m0 + srow)      * lda + skc;
  const unsigned short* Aptr2 = A  + (size_t)(m0 + 64 + srow) * lda + skc;
  const unsigned short* Bptr  = Bm + (size_t)(n0 + srow)      * ldb + skc;
  const unsigned short* Bptr2 = Bm + (size_t)(n0 + 64 + srow) * ldb + skc;

  i32x4 ar0 = *(const i32x4*)(Aptr);
  i32x4 ar1 = *(const i32x4*)(Aptr2);
  i32x4 br0 = *(const i32x4*)(Bptr);
  i32x4 br1 = *(const i32x4*)(Bptr2);
  *(i32x4*)&As[0][srow * 40 + skc]        = ar0;
  *(i32x4*)&As[0][(64 + srow) * 40 + skc] = ar1;
  *(i32x4*)&Bs[0][srow * 40 + skc]        = br0;
  *(i32x4*)&Bs[0][(64 + srow) * 40 + skc] = br1;
  __syncthreads();

  for (int kk = 0; kk < NK; ++kk) {
    const int cur = kk & 1;
    if (kk + 1 < NK) {
      const int ko = (kk + 1) << 5;
      ar0 = *(const i32x4*)(Aptr  + ko);
      ar1 = *(const i32x4*)(Aptr2 + ko);
      br0 = *(const i32x4*)(Bptr  + ko);
      br1 = *(const i32x4*)(Bptr2 + ko);
    }
    const bf16x8 a0 = *(const bf16x8*)&As[cur][(w * 32 + lr) * 40 + lk];
    const bf16x8 a1 = *(const bf16x8*)&As[cur][(w * 32 + 16 + lr) * 40 + lk];
#pragma unroll
    for (int nt = 0; nt < 8; ++nt) {
      const bf16x8 bb = *(const bf16x8*)&Bs[cur][(nt * 16 + lr) * 40 + lk];
      acc[0][nt] = __builtin_amdgcn_mfma_f32_16x16x32_bf16(a0, bb, acc[0][nt], 0, 0, 0);
      acc[1][nt] = __builtin_amdgcn_mfma_f32_16x16x32_bf16(a1, bb, acc[1][nt], 0, 0, 0);
    }
    __syncthreads();
    if (kk + 1 < NK) {
      const int nxt = cur ^ 1;
      *(i32x4*)&As[nxt][srow * 40 + skc]        = ar0;
      *(i32x4*)&As[nxt][(64 + srow) * 40 + skc] = ar1;
      *(i32x4*)&Bs[nxt][srow * 40 + skc]        = br0;
      *(i32x4*)&Bs[nxt][(64 + srow) * 40 + skc] = br1;
    }
    __syncthreads();
  }

#pragma unroll
  for (int mt = 0; mt < 2; ++mt) {
#pragma unroll
    for (int nt = 0; nt < 8; ++nt) {
      const f32x4 v = acc[mt][nt];
      const int gcol = n0 + nt * 16 + lr;
#pragma unroll
      for (int e = 0; e < 4; ++e) {
        const int grow = m0 + w * 32 + mt * 16 + (l >> 4) * 4 + e;
        const float val = v[e];
        if (EP == 0) {
          outF[(size_t)grow * N + gcol] = val + bias[gcol];
        } else if (EP == 1) {
          const float hsv = bf2f(A[(size_t)grow * lda + gcol]);
          outB[(size_t)grow * N + gcol] = f2bf(hsv - fmaxf(val, 0.f));
        } else if (EP == 2) {
          outB[(size_t)grow * N + gcol] = f2bf(fmaxf(val + bias[gcol], 0.f));
        } else {
          const int tt = grow >> 4;   // row = t*B + b
          const int bb2 = grow & 15;
          outF[((size_t)bb2 * T_ + tt) * H_ + gcol] = val + bias[gcol];
        }
      }
    }
  }
}

// ---------------------------------------------------------------- GRU scan
// Persistent dataflow kernel: 64 WGs x 256 thr. WG g owns H-cols [16g,16g+16)
// => W_hh rows {j, 1024+j, 2048+j}; A-fragments preloaded to registers once.
// Cross-WG h exchange via sc0/sc1 (coherence-point) loads/stores + per-WG
// flag array — NO threadfence (no L2 writeback/invalidate on the per-step
// critical path), NO atomic RMW serialization.
__global__ __launch_bounds__(256) void gru_scan_kernel(
    const unsigned short* __restrict__ Whh,   // [3072][1024] bf16
    const float* __restrict__ gates,          // [T*B][3072] (= x-gates + b_ih)
    const float* __restrict__ bhh,            // [3072]
    unsigned short* __restrict__ hs,          // [T+1][B][H] bf16; slice0 = 0
    int* __restrict__ flags) {                // [T+1][64], zeroed
  __shared__ __align__(16) float ghp[4][3][16][16];   // [wave][gate][batch][j]
  __shared__ __align__(16) unsigned short hlds[16][16];
  const int tid = threadIdx.x;
  const int g = blockIdx.x;
  const int w = tid >> 6;
  const int l = tid & 63;
  const int lr = l & 15;
  const int lk8 = (l >> 4) * 8;
  const int j0 = g * 16;

  // Preload A fragments: wave w covers K range [256w, 256w+256)
  bf16x8 af[3][8];
#pragma unroll
  for (int m = 0; m < 3; ++m) {
    const size_t row = (size_t)(m * H_ + j0 + lr);
#pragma unroll
    for (int kk = 0; kk < 8; ++kk) {
      const int k = w * 256 + kk * 32 + lk8;
      af[m][kk] = *(const bf16x8*)(Whh + row * H_ + k);
    }
  }
  const int jb = tid & 15;   // j within chunk
  const int bb = tid >> 4;   // batch
  const float bhr = bhh[j0 + jb];
  const float bhz = bhh[H_ + j0 + jb];
  const float bhn = bhh[2 * H_ + j0 + jb];
  float hprev = 0.f;

  for (int t = 0; t < T_; ++t) {
    // x-gates for this step (independent of h; issued before the wait)
    const size_t grow = ((size_t)t * B_ + bb) * G3_;
    const float gxr = gates[grow + j0 + jb];
    const float gxz = gates[grow + H_ + j0 + jb];
    const float gxn = gates[grow + 2 * H_ + j0 + jb];

    if (t > 0) {
      if (w == 0) {                       // 64 lanes poll 64 per-WG flags
        const int* fp = flags + t * 64 + l;
        while (true) {
          int f;
          asm volatile("global_load_dword %0, %1, off sc0 sc1\n\t"
                       "s_waitcnt vmcnt(0)"
                       : "=v"(f) : "v"(fp) : "memory");
          if (__ballot(f != 0) == ~0ull) break;
          __builtin_amdgcn_s_sleep(1);
        }
      }
      __syncthreads();
    }

    // load h_t fragments through the coherence point (bypass stale L1/L2)
    const unsigned short* hp = hs + (size_t)t * (B_ * H_) +
                               (size_t)lr * H_ + w * 256 + lk8;
    i32x4 u0, u1, u2, u3, u4, u5, u6, u7;
    asm volatile(
        "global_load_dwordx4 %0, %8, off sc0 sc1\n\t"
        "global_load_dwordx4 %1, %8, off offset:64 sc0 sc1\n\t"
        "global_load_dwordx4 %2, %8, off offset:128 sc0 sc1\n\t"
        "global_load_dwordx4 %3, %8, off offset:192 sc0 sc1\n\t"
        "global_load_dwordx4 %4, %8, off offset:256 sc0 sc1\n\t"
        "global_load_dwordx4 %5, %8, off offset:320 sc0 sc1\n\t"
        "global_load_dwordx4 %6, %8, off offset:384 sc0 sc1\n\t"
        "global_load_dwordx4 %7, %8, off offset:448 sc0 sc1\n\t"
        "s_waitcnt vmcnt(0)"
        : "=&v"(u0), "=&v"(u1), "=&v"(u2), "=&v"(u3),
          "=&v"(u4), "=&v"(u5), "=&v"(u6), "=&v"(u7)
        : "v"(hp)
        : "memory");
    bf16x8 hf[8];
    hf[0] = __builtin_bit_cast(bf16x8, u0);
    hf[1] = __builtin_bit_cast(bf16x8, u1);
    hf[2] = __builtin_bit_cast(bf16x8, u2);
    hf[3] = __builtin_bit_cast(bf16x8, u3);
    hf[4] = __builtin_bit_cast(bf16x8, u4);
    hf[5] = __builtin_bit_cast(bf16x8, u5);
    hf[6] = __builtin_bit_cast(bf16x8, u6);
    hf[7] = __builtin_bit_cast(bf16x8, u7);

    f32x4 C0 = (f32x4){0.f, 0.f, 0.f, 0.f}, C1 = C0, C2 = C0;
#pragma unroll
    for (int kk = 0; kk < 8; ++kk) {
      C0 = __builtin_amdgcn_mfma_f32_16x16x32_bf16(af[0][kk], hf[kk], C0, 0, 0, 0);
      C1 = __builtin_amdgcn_mfma_f32_16x16x32_bf16(af[1][kk], hf[kk], C1, 0, 0, 0);
      C2 = __builtin_amdgcn_mfma_f32_16x16x32_bf16(af[2][kk], hf[kk], C2, 0, 0, 0);
    }
    const int rbase = (l >> 4) * 4;
    *(f32x4*)&ghp[w][0][lr][rbase] = C0;
    *(f32x4*)&ghp[w][1][lr][rbase] = C1;
    *(f32x4*)&ghp[w][2][lr][rbase] = C2;
    __syncthreads();

    const float ghr = ghp[0][0][bb][jb] + ghp[1][0][bb][jb] +
                      ghp[2][0][bb][jb] + ghp[3][0][bb][jb] + bhr;
    const float ghz = ghp[0][1][bb][jb] + ghp[1][1][bb][jb] +
                      ghp[2][1][bb][jb] + ghp[3][1][bb][jb] + bhz;
    const float ghn = ghp[0][2][bb][jb] + ghp[1][2][bb][jb] +
                      ghp[2][2][bb][jb] + ghp[3][2][bb][jb] + bhn;
    const float r = 1.f / (1.f + __expf(-(gxr + ghr)));
    const float z = 1.f / (1.f + __expf(-(gxz + ghz)));
    const float xn = gxn + r * ghn;
    const float n = 2.f / (1.f + __expf(-2.f * xn)) - 1.f;
    const float hnew = (1.f - z) * n + z * hprev;   // carry stays fp32
    hprev = hnew;
    hlds[bb][jb] = f2bf(hnew);
    __syncthreads();

    // wave 0: publish our 16x16 chunk (32 lanes x 16B) through IF, then flag
    if (tid < 32) {
      const int bb2 = tid >> 1, half = tid & 1;
      unsigned short* sp = hs + ((size_t)(t + 1) * B_ + bb2) * H_ + j0 + half * 8;
      const i32x4 v = *(const i32x4*)&hlds[bb2][half * 8];
      asm volatile("global_store_dwordx4 %0, %1, off sc0 sc1"
                   :: "v"(sp), "v"(v) : "memory");
      asm volatile("s_waitcnt vmcnt(0)" ::: "memory");
      if (tid == 0) {
        const int one = 1;
        int* fp = flags + (t + 1) * 64 + g;
        asm volatile("global_store_dword %0, %1, off sc0 sc1"
                     :: "v"(fp), "v"(one) : "memory");
      }
    }
  }
}

// ---------------------------------------------------------------- launch
extern "C" void kernel_launch(void* const* d_in, const int* in_sizes, int n_in,
                              void* d_out, int out_size, void* d_ws, size_t ws_size,
                              hipStream_t stream) {
  (void)in_sizes; (void)n_in; (void)out_size; (void)ws_size;
  const float* x    = (const float*)d_in[0];
  const float* w3   = (const float*)d_in[1];
  const float* b3   = (const float*)d_in[2];
  const float* w5   = (const float*)d_in[3];
  const float* b5   = (const float*)d_in[4];
  const float* w7   = (const float*)d_in[5];
  const float* b7   = (const float*)d_in[6];
  const float* wih  = (const float*)d_in[7];
  const float* whh  = (const float*)d_in[8];
  const float* bih  = (const float*)d_in[9];
  const float* bhh  = (const float*)d_in[10];
  // d_in[11..14]: attn_* — dead code (softmax over length-1 axis == 1)
  const float* fiw1 = (const float*)d_in[15];
  const float* fib1 = (const float*)d_in[16];
  const float* fiw2 = (const float*)d_in[17];
  const float* fib2 = (const float*)d_in[18];
  const float* lat  = (const float*)d_in[19];

  char* ws = (char*)d_ws;
  size_t off = 0;
  auto alloc = [&](size_t bytes) -> void* {
    void* p = ws + off;
    off += (bytes + 255) & ~(size_t)255;
    return p;
  };
  unsigned short* whh_bf  = (unsigned short*)alloc((size_t)G3_ * H_ * 2);
  unsigned short* wih_bf  = (unsigned short*)alloc((size_t)G3_ * KIN_ * 2);
  unsigned short* latT_bf = (unsigned short*)alloc((size_t)H_ * H_ * 2);
  unsigned short* fiw1_bf = (unsigned short*)alloc((size_t)H_ * H_ * 2);
  unsigned short* fiw2_bf = (unsigned short*)alloc((size_t)H_ * H_ * 2);
  unsigned short* feat_bf = (unsigned short*)alloc((size_t)B_ * T_ * KIN_ * 2);
  float*          gates   = (float*)alloc((size_t)B_ * T_ * G3_ * 4);
  unsigned short* hsbuf   = (unsigned short*)alloc((size_t)(T_ + 1) * B_ * H_ * 2);
  unsigned short* inhib   = (unsigned short*)alloc((size_t)B_ * T_ * H_ * 2);
  unsigned short* y1      = (unsigned short*)alloc((size_t)B_ * T_ * H_ * 2);
  int*            flags   = (int*)alloc((size_t)(T_ + 1) * 64 * 4);

  hipMemsetAsync(flags, 0, (size_t)(T_ + 1) * 64 * 4, stream);
  hipMemsetAsync(hsbuf, 0, (size_t)B_ * H_ * 2, stream);   // h0 = 0

  cvt_bf16_kernel<<<2048, 256, 0, stream>>>(whh, whh_bf, G3_ * H_);
  cvt_bf16_kernel<<<1024, 256, 0, stream>>>(wih, wih_bf, G3_ * KIN_);
  cvt_bf16_kernel<<<1024, 256, 0, stream>>>(fiw1, fiw1_bf, H_ * H_);
  cvt_bf16_kernel<<<1024, 256, 0, stream>>>(fiw2, fiw2_bf, H_ * H_);
  transpose_bf16_kernel<<<1024, 256, 0, stream>>>(lat, latT_bf, H_, H_);

  conv_kernel<<<B_ * T_, 256, 0, stream>>>(x, w3, b3, w5, b5, w7, b7, feat_bf);

  {
    dim3 grid(G3_ / 128, (B_ * T_) / 128);
    gemm_kernel<0><<<grid, 256, 0, stream>>>(feat_bf, wih_bf, B_ * T_, G3_, KIN_,
                                             KIN_, KIN_, bih, gates, nullptr);
  }

  gru_scan_kernel<<<64, 256, 0, stream>>>(whh_bf, gates, bhh, hsbuf, flags);

  const unsigned short* hs1 = hsbuf + (size_t)B_ * H_;   // slices 1..T
  {
    dim3 grid(H_ / 128, (B_ * T_) / 128);
    gemm_kernel<1><<<grid, 256, 0, stream>>>(hs1, latT_bf, B_ * T_, H_, H_,
                                             H_, H_, nullptr, nullptr, inhib);
    gemm_kernel<2><<<grid, 256, 0, stream>>>(inhib, fiw1_bf, B_ * T_, H_, H_,
                                             H_, H_, fib1, nullptr, y1);
    gemm_kernel<3><<<grid, 256, 0, stream>>>(y1, fiw2_bf, B_ * T_, H_, H_,
                                             H_, H_, fib2, (float*)d_out, nullptr);
  }

  ones_kernel<<<16, 256, 0, stream>>>((float*)d_out + (size_t)B_ * T_ * H_, B_ * T_);
}

// Round 3
// 1081.212 us; speedup vs baseline: 3.2704x; 1.0556x over previous
//
#include <hip/hip_runtime.h>
#include <stdint.h>
#include <stddef.h>

#define B_   16
#define T_   256
#define L_   1024
#define H_   1024
#define G3_  3072
#define KIN_ 96

// NaN bf16 pattern: can never be produced by the GRU (|h| bounded, no inf/nan arithmetic)
#define SENT_     0x7FC1
#define SENT_X2_  0x7FC17FC1u

typedef __attribute__((ext_vector_type(8))) __bf16 bf16x8;
typedef __attribute__((ext_vector_type(4))) float  f32x4;
typedef __attribute__((ext_vector_type(4))) int    i32x4;

static __device__ __forceinline__ unsigned short f2bf(float x) {
  unsigned int u = __builtin_bit_cast(unsigned int, x);
  u += 0x7FFFu + ((u >> 16) & 1u);           // RNE
  return (unsigned short)(u >> 16);
}
static __device__ __forceinline__ float bf2f(unsigned short s) {
  unsigned int u = ((unsigned int)s) << 16;
  return __builtin_bit_cast(float, u);
}

// ---------------------------------------------------------------- converts
// Fused bf16 convert of the 4 weight matrices (one launch instead of four).
__global__ void cvt4_kernel(const float* __restrict__ s0, unsigned short* __restrict__ d0,
                            const float* __restrict__ s1, unsigned short* __restrict__ d1,
                            const float* __restrict__ s2, unsigned short* __restrict__ d2,
                            const float* __restrict__ s3, unsigned short* __restrict__ d3) {
  const int n0 = G3_ * H_;            // whh  3145728
  const int n1 = n0 + G3_ * KIN_;     // wih  +294912
  const int n2 = n1 + H_ * H_;        // fiw1 +1048576
  const int n3 = n2 + H_ * H_;        // fiw2 +1048576
  int i = blockIdx.x * 256 + threadIdx.x;
  const int stride = gridDim.x * 256;
  for (; i < n3; i += stride) {
    if (i < n0)      d0[i]      = f2bf(s0[i]);
    else if (i < n1) d1[i - n0] = f2bf(s1[i - n0]);
    else if (i < n2) d2[i - n1] = f2bf(s2[i - n1]);
    else             d3[i - n2] = f2bf(s3[i - n2]);
  }
}

__global__ void transpose_bf16_kernel(const float* __restrict__ in,
                                      unsigned short* __restrict__ out,
                                      int R, int C) {
  int i = blockIdx.x * 256 + threadIdx.x;
  int n = R * C, stride = gridDim.x * 256;
  for (; i < n; i += stride) {
    int r = i / C, c = i % C;
    out[(size_t)c * R + r] = f2bf(in[i]);
  }
}

__global__ void ones_kernel(float* __restrict__ p, int n) {
  int i = blockIdx.x * 256 + threadIdx.x;
  if (i < n) p[i] = 1.0f;
}

// Fill hs[1..T] with the sentinel pattern, stores at the coherence point so the
// scan kernel's sc0/sc1 loads are guaranteed to see it.
__global__ void fill_sent_kernel(unsigned int* __restrict__ p, int n) {
  int i = blockIdx.x * 256 + threadIdx.x;
  const int stride = gridDim.x * 256;
  const unsigned int v = SENT_X2_;
  for (; i < n; i += stride) {
    unsigned int* q = p + i;
    asm volatile("global_store_dword %0, %1, off sc0 sc1" :: "v"(q), "v"(v) : "memory");
  }
}

// ---------------------------------------------------------------- conv+pool
__global__ __launch_bounds__(256) void conv_kernel(
    const float* __restrict__ x,
    const float* __restrict__ w3, const float* __restrict__ b3,
    const float* __restrict__ w5, const float* __restrict__ b5,
    const float* __restrict__ w7, const float* __restrict__ b7,
    unsigned short* __restrict__ feat) {
  __shared__ float xpad[L_ + 8];
  __shared__ float wlds[96][8];
  __shared__ float blds[96];
  __shared__ float wmax[4][96];
  const int tid = threadIdx.x;
  const int rid = blockIdx.x;          // b*T + t
  const int b = rid >> 8;
  const int t = rid & 255;
  const float* xr = x + (size_t)rid * L_;
  for (int off = tid; off < L_; off += 256) xpad[off + 3] = xr[off];
  if (tid < 3) xpad[tid] = 0.f;
  if (tid >= 3 && tid < 8) xpad[L_ + tid] = 0.f;
  if (tid < 96) {
    const int f = tid;
    float wv[8];
#pragma unroll
    for (int k = 0; k < 8; ++k) wv[k] = 0.f;
    float bv;
    if (f < 32)      { for (int k = 0; k < 3; ++k) wv[k + 2] = w3[f * 3 + k]; bv = b3[f]; }
    else if (f < 64) { int ff = f - 32; for (int k = 0; k < 5; ++k) wv[k + 1] = w5[ff * 5 + k]; bv = b5[ff]; }
    else             { int ff = f - 64; for (int k = 0; k < 7; ++k) wv[k] = w7[ff * 7 + k]; bv = b7[ff]; }
#pragma unroll
    for (int k = 0; k < 8; ++k) wlds[f][k] = wv[k];
    blds[f] = bv;
  }
  __syncthreads();
  const int w = tid >> 6, lane = tid & 63;
  const int p0 = w * 256 + lane * 4;
  float xv[10];
#pragma unroll
  for (int i = 0; i < 10; ++i) xv[i] = xpad[p0 + i];
  for (int f = 0; f < 96; ++f) {
    float a0 = 0.f, a1 = 0.f, a2 = 0.f, a3 = 0.f;
#pragma unroll
    for (int k = 0; k < 7; ++k) {
      const float wk = wlds[f][k];
      a0 = fmaf(wk, xv[k],     a0);
      a1 = fmaf(wk, xv[k + 1], a1);
      a2 = fmaf(wk, xv[k + 2], a2);
      a3 = fmaf(wk, xv[k + 3], a3);
    }
    float m = fmaxf(fmaxf(a0, a1), fmaxf(a2, a3));
#pragma unroll
    for (int d = 1; d < 64; d <<= 1) m = fmaxf(m, __shfl_xor(m, d, 64));
    if (lane == 0) wmax[w][f] = m;
  }
  __syncthreads();
  if (tid < 96) {
    float m = fmaxf(fmaxf(wmax[0][tid], wmax[1][tid]),
                    fmaxf(wmax[2][tid], wmax[3][tid]));
    m += blds[tid];
    m = m > 0.f ? m : 0.f;
    feat[(size_t)(t * B_ + b) * KIN_ + tid] = f2bf(m);   // row = t*B + b
  }
}

// ---------------------------------------------------------------- GEMM
// C[M,N] = A[M,K] * B[N,K]^T  (both bf16, row-major). 128x128 tile, BK=32,
// 4 waves, double-buffered LDS, padded stride 40.
template <int EP>
__global__ __launch_bounds__(256) void gemm_kernel(
    const unsigned short* __restrict__ A,
    const unsigned short* __restrict__ Bm,
    int M, int N, int K, int lda, int ldb,
    const float* __restrict__ bias,
    float* __restrict__ outF,
    unsigned short* __restrict__ outB) {
  __shared__ __align__(16) unsigned short As[2][128 * 40];
  __shared__ __align__(16) unsigned short Bs[2][128 * 40];
  const int tid = threadIdx.x;
  const int n0 = blockIdx.x * 128;
  const int m0 = blockIdx.y * 128;
  const int w = tid >> 6;
  const int l = tid & 63;
  const int lr = l & 15;
  const int lk = (l >> 4) * 8;
  const int srow = tid >> 2;
  const int skc = (tid & 3) * 8;

  f32x4 acc[2][8];
#pragma unroll
  for (int i = 0; i < 2; ++i)
#pragma unroll
    for (int j = 0; j < 8; ++j) acc[i][j] = (f32x4){0.f, 0.f, 0.f, 0.f};

  const int NK = K >> 5;
  const unsigned short* Aptr  = A  + (size_t)(m0 + srow)      * lda + skc;
  const unsigned short* Aptr2 = A  + (size_t)(m0 + 64 + srow) * lda + skc;
  const unsigned short* Bptr  = Bm + (size_t)(n0 + srow)      * ldb + skc;
  const unsigned short* Bptr2 = Bm + (size_t)(n0 + 64 + srow) * ldb + skc;

  i32x4 ar0 = *(const i32x4*)(Aptr);
  i32x4 ar1 = *(const i32x4*)(Aptr2);
  i32x4 br0 = *(const i32x4*)(Bptr);
  i32x4 br1 = *(const i32x4*)(Bptr2);
  *(i32x4*)&As[0][srow * 40 + skc]        = ar0;
  *(i32x4*)&As[0][(64 + srow) * 40 + skc] = ar1;
  *(i32x4*)&Bs[0][srow * 40 + skc]        = br0;
  *(i32x4*)&Bs[0][(64 + srow) * 40 + skc] = br1;
  __syncthreads();

  for (int kk = 0; kk < NK; ++kk) {
    const int cur = kk & 1;
    if (kk + 1 < NK) {
      const int ko = (kk + 1) << 5;
      ar0 = *(const i32x4*)(Aptr  + ko);
      ar1 = *(const i32x4*)(Aptr2 + ko);
      br0 = *(const i32x4*)(Bptr  + ko);
      br1 = *(const i32x4*)(Bptr2 + ko);
    }
    const bf16x8 a0 = *(const bf16x8*)&As[cur][(w * 32 + lr) * 40 + lk];
    const bf16x8 a1 = *(const bf16x8*)&As[cur][(w * 32 + 16 + lr) * 40 + lk];
#pragma unroll
    for (int nt = 0; nt < 8; ++nt) {
      const bf16x8 bb = *(const bf16x8*)&Bs[cur][(nt * 16 + lr) * 40 + lk];
      acc[0][nt] = __builtin_amdgcn_mfma_f32_16x16x32_bf16(a0, bb, acc[0][nt], 0, 0, 0);
      acc[1][nt] = __builtin_amdgcn_mfma_f32_16x16x32_bf16(a1, bb, acc[1][nt], 0, 0, 0);
    }
    __syncthreads();
    if (kk + 1 < NK) {
      const int nxt = cur ^ 1;
      *(i32x4*)&As[nxt][srow * 40 + skc]        = ar0;
      *(i32x4*)&As[nxt][(64 + srow) * 40 + skc] = ar1;
      *(i32x4*)&Bs[nxt][srow * 40 + skc]        = br0;
      *(i32x4*)&Bs[nxt][(64 + srow) * 40 + skc] = br1;
    }
    __syncthreads();
  }

#pragma unroll
  for (int mt = 0; mt < 2; ++mt) {
#pragma unroll
    for (int nt = 0; nt < 8; ++nt) {
      const f32x4 v = acc[mt][nt];
      const int gcol = n0 + nt * 16 + lr;
#pragma unroll
      for (int e = 0; e < 4; ++e) {
        const int grow = m0 + w * 32 + mt * 16 + (l >> 4) * 4 + e;
        const float val = v[e];
        if (EP == 0) {
          outF[(size_t)grow * N + gcol] = val + bias[gcol];
        } else if (EP == 1) {
          const float hsv = bf2f(A[(size_t)grow * lda + gcol]);
          outB[(size_t)grow * N + gcol] = f2bf(hsv - fmaxf(val, 0.f));
        } else if (EP == 2) {
          outB[(size_t)grow * N + gcol] = f2bf(fmaxf(val + bias[gcol], 0.f));
        } else {
          const int tt = grow >> 4;   // row = t*B + b
          const int bb2 = grow & 15;
          outF[((size_t)bb2 * T_ + tt) * H_ + gcol] = val + bias[gcol];
        }
      }
    }
  }
}

// ---------------------------------------------------------------- GRU scan
// Persistent dataflow kernel: 64 WGs x 256 thr. WG g owns H-cols [16g,16g+16).
// Flagless sentinel protocol: hs[1..T] pre-filled with bf16 NaN 0x7FC1 (which
// the GRU can never produce). Producers store 16B units at the coherence point
// (sc0 sc1) with NO drain and NO flag; each consumer wave polls ITS OWN 8
// fragments and validates one element per 16B unit (units are written whole).
// Per-wave independent progress: no barrier before the load/MFMA phase.
__global__ __launch_bounds__(256, 1) void gru_scan_kernel(
    const unsigned short* __restrict__ Whh,   // [3072][1024] bf16
    const float* __restrict__ gates,          // [T*B][3072] (= x-gates + b_ih)
    const float* __restrict__ bhh,            // [3072]
    unsigned short* __restrict__ hs) {        // [T+1][B][H] bf16; slice0 = 0
  __shared__ __align__(16) float ghp[4][3][16][16];   // [wave][gate][batch][j]
  __shared__ __align__(16) unsigned short hlds[16][16];
  const int tid = threadIdx.x;
  const int g = blockIdx.x;
  const int w = tid >> 6;
  const int l = tid & 63;
  const int lr = l & 15;
  const int lk8 = (l >> 4) * 8;
  const int j0 = g * 16;

  // Preload A fragments: wave w covers K range [256w, 256w+256)
  bf16x8 af[3][8];
#pragma unroll
  for (int m = 0; m < 3; ++m) {
    const size_t row = (size_t)(m * H_ + j0 + lr);
#pragma unroll
    for (int kk = 0; kk < 8; ++kk) {
      const int k = w * 256 + kk * 32 + lk8;
      af[m][kk] = *(const bf16x8*)(Whh + row * H_ + k);
    }
  }
  const int jb = tid & 15;   // j within chunk
  const int bb = tid >> 4;   // batch
  const float bhr = bhh[j0 + jb];
  const float bhz = bhh[H_ + j0 + jb];
  const float bhn = bhh[2 * H_ + j0 + jb];
  float hprev = 0.f;

  for (int t = 0; t < T_; ++t) {
    // x-gates for this step (independent of h)
    const size_t grow = ((size_t)t * B_ + bb) * G3_;
    const float gxr = gates[grow + j0 + jb];
    const float gxz = gates[grow + H_ + j0 + jb];
    const float gxn = gates[grow + 2 * H_ + j0 + jb];

    // Poll-load h_t fragments through the coherence point until sentinel-free.
    const unsigned short* hp = hs + (size_t)t * (B_ * H_) +
                               (size_t)lr * H_ + w * 256 + lk8;
    i32x4 u0, u1, u2, u3, u4, u5, u6, u7;
    while (true) {
      asm volatile(
          "global_load_dwordx4 %0, %8, off sc0 sc1\n\t"
          "global_load_dwordx4 %1, %8, off offset:64 sc0 sc1\n\t"
          "global_load_dwordx4 %2, %8, off offset:128 sc0 sc1\n\t"
          "global_load_dwordx4 %3, %8, off offset:192 sc0 sc1\n\t"
          "global_load_dwordx4 %4, %8, off offset:256 sc0 sc1\n\t"
          "global_load_dwordx4 %5, %8, off offset:320 sc0 sc1\n\t"
          "global_load_dwordx4 %6, %8, off offset:384 sc0 sc1\n\t"
          "global_load_dwordx4 %7, %8, off offset:448 sc0 sc1\n\t"
          "s_waitcnt vmcnt(0)"
          : "=&v"(u0), "=&v"(u1), "=&v"(u2), "=&v"(u3),
            "=&v"(u4), "=&v"(u5), "=&v"(u6), "=&v"(u7)
          : "v"(hp)
          : "memory");
      const int ok = ((u0[0] & 0xFFFF) != SENT_) & ((u1[0] & 0xFFFF) != SENT_) &
                     ((u2[0] & 0xFFFF) != SENT_) & ((u3[0] & 0xFFFF) != SENT_) &
                     ((u4[0] & 0xFFFF) != SENT_) & ((u5[0] & 0xFFFF) != SENT_) &
                     ((u6[0] & 0xFFFF) != SENT_) & ((u7[0] & 0xFFFF) != SENT_);
      if (__ballot(ok) == ~0ull) break;
    }
    bf16x8 hf[8];
    hf[0] = __builtin_bit_cast(bf16x8, u0);
    hf[1] = __builtin_bit_cast(bf16x8, u1);
    hf[2] = __builtin_bit_cast(bf16x8, u2);
    hf[3] = __builtin_bit_cast(bf16x8, u3);
    hf[4] = __builtin_bit_cast(bf16x8, u4);
    hf[5] = __builtin_bit_cast(bf16x8, u5);
    hf[6] = __builtin_bit_cast(bf16x8, u6);
    hf[7] = __builtin_bit_cast(bf16x8, u7);

    f32x4 C0 = (f32x4){0.f, 0.f, 0.f, 0.f}, C1 = C0, C2 = C0;
#pragma unroll
    for (int kk = 0; kk < 8; ++kk) {
      C0 = __builtin_amdgcn_mfma_f32_16x16x32_bf16(af[0][kk], hf[kk], C0, 0, 0, 0);
      C1 = __builtin_amdgcn_mfma_f32_16x16x32_bf16(af[1][kk], hf[kk], C1, 0, 0, 0);
      C2 = __builtin_amdgcn_mfma_f32_16x16x32_bf16(af[2][kk], hf[kk], C2, 0, 0, 0);
    }
    // safe: we passed the previous step's second barrier, so all ghp reads done
    const int rbase = (l >> 4) * 4;
    *(f32x4*)&ghp[w][0][lr][rbase] = C0;
    *(f32x4*)&ghp[w][1][lr][rbase] = C1;
    *(f32x4*)&ghp[w][2][lr][rbase] = C2;
    __syncthreads();

    const float ghr = ghp[0][0][bb][jb] + ghp[1][0][bb][jb] +
                      ghp[2][0][bb][jb] + ghp[3][0][bb][jb] + bhr;
    const float ghz = ghp[0][1][bb][jb] + ghp[1][1][bb][jb] +
                      ghp[2][1][bb][jb] + ghp[3][1][bb][jb] + bhz;
    const float ghn = ghp[0][2][bb][jb] + ghp[1][2][bb][jb] +
                      ghp[2][2][bb][jb] + ghp[3][2][bb][jb] + bhn;
    const float r = 1.f / (1.f + __expf(-(gxr + ghr)));
    const float z = 1.f / (1.f + __expf(-(gxz + ghz)));
    const float xn = gxn + r * ghn;
    const float n = 2.f / (1.f + __expf(-2.f * xn)) - 1.f;
    const float hnew = (1.f - z) * n + z * hprev;   // carry stays fp32
    hprev = hnew;
    hlds[bb][jb] = f2bf(hnew);
    __syncthreads();

    // publish our 16x16 chunk (32 lanes x 16B) — data IS the signal
    if (tid < 32) {
      const int bb2 = tid >> 1, half = tid & 1;
      unsigned short* sp = hs + ((size_t)(t + 1) * B_ + bb2) * H_ + j0 + half * 8;
      const i32x4 v = *(const i32x4*)&hlds[bb2][half * 8];
      asm volatile("global_store_dwordx4 %0, %1, off sc0 sc1"
                   :: "v"(sp), "v"(v) : "memory");
    }
  }
}

// ---------------------------------------------------------------- launch
extern "C" void kernel_launch(void* const* d_in, const int* in_sizes, int n_in,
                              void* d_out, int out_size, void* d_ws, size_t ws_size,
                              hipStream_t stream) {
  (void)in_sizes; (void)n_in; (void)out_size; (void)ws_size;
  const float* x    = (const float*)d_in[0];
  const float* w3   = (const float*)d_in[1];
  const float* b3   = (const float*)d_in[2];
  const float* w5   = (const float*)d_in[3];
  const float* b5   = (const float*)d_in[4];
  const float* w7   = (const float*)d_in[5];
  const float* b7   = (const float*)d_in[6];
  const float* wih  = (const float*)d_in[7];
  const float* whh  = (const float*)d_in[8];
  const float* bih  = (const float*)d_in[9];
  const float* bhh  = (const float*)d_in[10];
  // d_in[11..14]: attn_* — dead code (softmax over length-1 axis == 1)
  const float* fiw1 = (const float*)d_in[15];
  const float* fib1 = (const float*)d_in[16];
  const float* fiw2 = (const float*)d_in[17];
  const float* fib2 = (const float*)d_in[18];
  const float* lat  = (const float*)d_in[19];

  char* ws = (char*)d_ws;
  size_t off = 0;
  auto alloc = [&](size_t bytes) -> void* {
    void* p = ws + off;
    off += (bytes + 255) & ~(size_t)255;
    return p;
  };
  unsigned short* whh_bf  = (unsigned short*)alloc((size_t)G3_ * H_ * 2);
  unsigned short* wih_bf  = (unsigned short*)alloc((size_t)G3_ * KIN_ * 2);
  unsigned short* latT_bf = (unsigned short*)alloc((size_t)H_ * H_ * 2);
  unsigned short* fiw1_bf = (unsigned short*)alloc((size_t)H_ * H_ * 2);
  unsigned short* fiw2_bf = (unsigned short*)alloc((size_t)H_ * H_ * 2);
  unsigned short* feat_bf = (unsigned short*)alloc((size_t)B_ * T_ * KIN_ * 2);
  float*          gates   = (float*)alloc((size_t)B_ * T_ * G3_ * 4);
  unsigned short* hsbuf   = (unsigned short*)alloc((size_t)(T_ + 1) * B_ * H_ * 2);
  unsigned short* inhib   = (unsigned short*)alloc((size_t)B_ * T_ * H_ * 2);
  unsigned short* y1      = (unsigned short*)alloc((size_t)B_ * T_ * H_ * 2);

  hipMemsetAsync(hsbuf, 0, (size_t)B_ * H_ * 2, stream);   // h0 = 0
  fill_sent_kernel<<<1024, 256, 0, stream>>>(
      (unsigned int*)(hsbuf + (size_t)B_ * H_), T_ * B_ * H_ / 2);

  cvt4_kernel<<<2048, 256, 0, stream>>>(whh, whh_bf, wih, wih_bf,
                                        fiw1, fiw1_bf, fiw2, fiw2_bf);
  transpose_bf16_kernel<<<1024, 256, 0, stream>>>(lat, latT_bf, H_, H_);

  conv_kernel<<<B_ * T_, 256, 0, stream>>>(x, w3, b3, w5, b5, w7, b7, feat_bf);

  {
    dim3 grid(G3_ / 128, (B_ * T_) / 128);
    gemm_kernel<0><<<grid, 256, 0, stream>>>(feat_bf, wih_bf, B_ * T_, G3_, KIN_,
                                             KIN_, KIN_, bih, gates, nullptr);
  }

  gru_scan_kernel<<<64, 256, 0, stream>>>(whh_bf, gates, bhh, hsbuf);

  const unsigned short* hs1 = hsbuf + (size_t)B_ * H_;   // slices 1..T
  {
    dim3 grid(H_ / 128, (B_ * T_) / 128);
    gemm_kernel<1><<<grid, 256, 0, stream>>>(hs1, latT_bf, B_ * T_, H_, H_,
                                             H_, H_, nullptr, nullptr, inhib);
    gemm_kernel<2><<<grid, 256, 0, stream>>>(inhib, fiw1_bf, B_ * T_, H_, H_,
                                             H_, H_, fib1, nullptr, y1);
    gemm_kernel<3><<<grid, 256, 0, stream>>>(y1, fiw2_bf, B_ * T_, H_, H_,
                                             H_, H_, fib2, (float*)d_out, nullptr);
  }

  ones_kernel<<<16, 256, 0, stream>>>((float*)d_out + (size_t)B_ * T_ * H_, B_ * T_);
}

// Round 4
// 1031.261 us; speedup vs baseline: 3.4288x; 1.0484x over previous
//
#include <hip/hip_runtime.h>
#include <stdint.h>
#include <stddef.h>

#define B_   16
#define T_   256
#define L_   1024
#define H_   1024
#define G3_  3072
#define KIN_ 96

// NaN bf16 pattern: can never be produced by the GRU (|h| <= 1, finite arithmetic)
#define SENT_     0x7FC1
#define SENT_X2_  0x7FC17FC1u

typedef __attribute__((ext_vector_type(8))) __bf16 bf16x8;
typedef __attribute__((ext_vector_type(4))) float  f32x4;
typedef __attribute__((ext_vector_type(4))) int    i32x4;

static __device__ __forceinline__ unsigned short f2bf(float x) {
  unsigned int u = __builtin_bit_cast(unsigned int, x);
  u += 0x7FFFu + ((u >> 16) & 1u);           // RNE
  return (unsigned short)(u >> 16);
}
static __device__ __forceinline__ float bf2f(unsigned short s) {
  unsigned int u = ((unsigned int)s) << 16;
  return __builtin_bit_cast(float, u);
}
// nonzero iff either 16-bit half of d equals the sentinel
static __device__ __forceinline__ unsigned sentmask(unsigned d) {
  const unsigned x = d ^ SENT_X2_;
  return (x - 0x00010001u) & ~x & 0x80008000u;
}

// ---------------------------------------------------------------- converts
__global__ void cvt4_kernel(const float* __restrict__ s0, unsigned short* __restrict__ d0,
                            const float* __restrict__ s1, unsigned short* __restrict__ d1,
                            const float* __restrict__ s2, unsigned short* __restrict__ d2,
                            const float* __restrict__ s3, unsigned short* __restrict__ d3) {
  const int n0 = G3_ * H_;            // whh
  const int n1 = n0 + G3_ * KIN_;     // wih
  const int n2 = n1 + H_ * H_;        // fiw1
  const int n3 = n2 + H_ * H_;        // fiw2
  int i = blockIdx.x * 256 + threadIdx.x;
  const int stride = gridDim.x * 256;
  for (; i < n3; i += stride) {
    if (i < n0)      d0[i]      = f2bf(s0[i]);
    else if (i < n1) d1[i - n0] = f2bf(s1[i - n0]);
    else if (i < n2) d2[i - n1] = f2bf(s2[i - n1]);
    else             d3[i - n2] = f2bf(s3[i - n2]);
  }
}

__global__ void transpose_bf16_kernel(const float* __restrict__ in,
                                      unsigned short* __restrict__ out,
                                      int R, int C) {
  int i = blockIdx.x * 256 + threadIdx.x;
  int n = R * C, stride = gridDim.x * 256;
  for (; i < n; i += stride) {
    int r = i / C, c = i % C;
    out[(size_t)c * R + r] = f2bf(in[i]);
  }
}

__global__ void ones_kernel(float* __restrict__ p, int n) {
  int i = blockIdx.x * 256 + threadIdx.x;
  if (i < n) p[i] = 1.0f;
}

__global__ void fill_sent_kernel(unsigned int* __restrict__ p, int n) {
  int i = blockIdx.x * 256 + threadIdx.x;
  const int stride = gridDim.x * 256;
  const unsigned int v = SENT_X2_;
  for (; i < n; i += stride) {
    unsigned int* q = p + i;
    asm volatile("global_store_dword %0, %1, off sc0 sc1" :: "v"(q), "v"(v) : "memory");
  }
}

// ---------------------------------------------------------------- conv+pool
__global__ __launch_bounds__(256) void conv_kernel(
    const float* __restrict__ x,
    const float* __restrict__ w3, const float* __restrict__ b3,
    const float* __restrict__ w5, const float* __restrict__ b5,
    const float* __restrict__ w7, const float* __restrict__ b7,
    unsigned short* __restrict__ feat) {
  __shared__ float xpad[L_ + 8];
  __shared__ float wlds[96][8];
  __shared__ float blds[96];
  __shared__ float wmax[4][96];
  const int tid = threadIdx.x;
  const int rid = blockIdx.x;          // b*T + t
  const int b = rid >> 8;
  const int t = rid & 255;
  const float* xr = x + (size_t)rid * L_;
  for (int off = tid; off < L_; off += 256) xpad[off + 3] = xr[off];
  if (tid < 3) xpad[tid] = 0.f;
  if (tid >= 3 && tid < 8) xpad[L_ + tid] = 0.f;
  if (tid < 96) {
    const int f = tid;
    float wv[8];
#pragma unroll
    for (int k = 0; k < 8; ++k) wv[k] = 0.f;
    float bv;
    if (f < 32)      { for (int k = 0; k < 3; ++k) wv[k + 2] = w3[f * 3 + k]; bv = b3[f]; }
    else if (f < 64) { int ff = f - 32; for (int k = 0; k < 5; ++k) wv[k + 1] = w5[ff * 5 + k]; bv = b5[ff]; }
    else             { int ff = f - 64; for (int k = 0; k < 7; ++k) wv[k] = w7[ff * 7 + k]; bv = b7[ff]; }
#pragma unroll
    for (int k = 0; k < 8; ++k) wlds[f][k] = wv[k];
    blds[f] = bv;
  }
  __syncthreads();
  const int w = tid >> 6, lane = tid & 63;
  const int p0 = w * 256 + lane * 4;
  float xv[10];
#pragma unroll
  for (int i = 0; i < 10; ++i) xv[i] = xpad[p0 + i];
  for (int f = 0; f < 96; ++f) {
    float a0 = 0.f, a1 = 0.f, a2 = 0.f, a3 = 0.f;
#pragma unroll
    for (int k = 0; k < 7; ++k) {
      const float wk = wlds[f][k];
      a0 = fmaf(wk, xv[k],     a0);
      a1 = fmaf(wk, xv[k + 1], a1);
      a2 = fmaf(wk, xv[k + 2], a2);
      a3 = fmaf(wk, xv[k + 3], a3);
    }
    float m = fmaxf(fmaxf(a0, a1), fmaxf(a2, a3));
#pragma unroll
    for (int d = 1; d < 64; d <<= 1) m = fmaxf(m, __shfl_xor(m, d, 64));
    if (lane == 0) wmax[w][f] = m;
  }
  __syncthreads();
  if (tid < 96) {
    float m = fmaxf(fmaxf(wmax[0][tid], wmax[1][tid]),
                    fmaxf(wmax[2][tid], wmax[3][tid]));
    m += blds[tid];
    m = m > 0.f ? m : 0.f;
    feat[(size_t)(t * B_ + b) * KIN_ + tid] = f2bf(m);   // row = t*B + b
  }
}

// ---------------------------------------------------------------- GEMM
// C[M,N] = A[M,K] * B[N,K]^T  (both bf16, row-major). 128x128 tile, BK=32,
// 4 waves, double-buffered LDS, padded stride 40.
template <int EP>
__global__ __launch_bounds__(256) void gemm_kernel(
    const unsigned short* __restrict__ A,
    const unsigned short* __restrict__ Bm,
    int M, int N, int K, int lda, int ldb,
    const float* __restrict__ bias,
    float* __restrict__ outF,
    unsigned short* __restrict__ outB) {
  __shared__ __align__(16) unsigned short As[2][128 * 40];
  __shared__ __align__(16) unsigned short Bs[2][128 * 40];
  const int tid = threadIdx.x;
  const int n0 = blockIdx.x * 128;
  const int m0 = blockIdx.y * 128;
  const int w = tid >> 6;
  const int l = tid & 63;
  const int lr = l & 15;
  const int lk = (l >> 4) * 8;
  const int srow = tid >> 2;
  const int skc = (tid & 3) * 8;

  f32x4 acc[2][8];
#pragma unroll
  for (int i = 0; i < 2; ++i)
#pragma unroll
    for (int j = 0; j < 8; ++j) acc[i][j] = (f32x4){0.f, 0.f, 0.f, 0.f};

  const int NK = K >> 5;
  const unsigned short* Aptr  = A  + (size_t)(m0 + srow)      * lda + skc;
  const unsigned short* Aptr2 = A  + (size_t)(m0 + 64 + srow) * lda + skc;
  const unsigned short* Bptr  = Bm + (size_t)(n0 + srow)      * ldb + skc;
  const unsigned short* Bptr2 = Bm + (size_t)(n0 + 64 + srow) * ldb + skc;

  i32x4 ar0 = *(const i32x4*)(Aptr);
  i32x4 ar1 = *(const i32x4*)(Aptr2);
  i32x4 br0 = *(const i32x4*)(Bptr);
  i32x4 br1 = *(const i32x4*)(Bptr2);
  *(i32x4*)&As[0][srow * 40 + skc]        = ar0;
  *(i32x4*)&As[0][(64 + srow) * 40 + skc] = ar1;
  *(i32x4*)&Bs[0][srow * 40 + skc]        = br0;
  *(i32x4*)&Bs[0][(64 + srow) * 40 + skc] = br1;
  __syncthreads();

  for (int kk = 0; kk < NK; ++kk) {
    const int cur = kk & 1;
    if (kk + 1 < NK) {
      const int ko = (kk + 1) << 5;
      ar0 = *(const i32x4*)(Aptr  + ko);
      ar1 = *(const i32x4*)(Aptr2 + ko);
      br0 = *(const i32x4*)(Bptr  + ko);
      br1 = *(const i32x4*)(Bptr2 + ko);
    }
    const bf16x8 a0 = *(const bf16x8*)&As[cur][(w * 32 + lr) * 40 + lk];
    const bf16x8 a1 = *(const bf16x8*)&As[cur][(w * 32 + 16 + lr) * 40 + lk];
#pragma unroll
    for (int nt = 0; nt < 8; ++nt) {
      const bf16x8 bb = *(const bf16x8*)&Bs[cur][(nt * 16 + lr) * 40 + lk];
      acc[0][nt] = __builtin_amdgcn_mfma_f32_16x16x32_bf16(a0, bb, acc[0][nt], 0, 0, 0);
      acc[1][nt] = __builtin_amdgcn_mfma_f32_16x16x32_bf16(a1, bb, acc[1][nt], 0, 0, 0);
    }
    __syncthreads();
    if (kk + 1 < NK) {
      const int nxt = cur ^ 1;
      *(i32x4*)&As[nxt][srow * 40 + skc]        = ar0;
      *(i32x4*)&As[nxt][(64 + srow) * 40 + skc] = ar1;
      *(i32x4*)&Bs[nxt][srow * 40 + skc]        = br0;
      *(i32x4*)&Bs[nxt][(64 + srow) * 40 + skc] = br1;
    }
    __syncthreads();
  }

#pragma unroll
  for (int mt = 0; mt < 2; ++mt) {
#pragma unroll
    for (int nt = 0; nt < 8; ++nt) {
      const f32x4 v = acc[mt][nt];
      const int gcol = n0 + nt * 16 + lr;
#pragma unroll
      for (int e = 0; e < 4; ++e) {
        const int grow = m0 + w * 32 + mt * 16 + (l >> 4) * 4 + e;
        const float val = v[e];
        if (EP == 0) {
          outF[(size_t)grow * N + gcol] = val + bias[gcol];
        } else if (EP == 1) {
          const float hsv = bf2f(A[(size_t)grow * lda + gcol]);
          outB[(size_t)grow * N + gcol] = f2bf(hsv - fmaxf(val, 0.f));
        } else if (EP == 2) {
          outB[(size_t)grow * N + gcol] = f2bf(fmaxf(val + bias[gcol], 0.f));
        } else {
          const int tt = grow >> 4;   // row = t*B + b
          const int bb2 = grow & 15;
          outF[((size_t)bb2 * T_ + tt) * H_ + gcol] = val + bias[gcol];
        }
      }
    }
  }
}

// ---------------------------------------------------------------- GRU scan
// Persistent dataflow kernel: 64 WGs x 512 thr (8 waves). WG g owns H-cols
// [16g,16g+16); wave w covers K range [128w,128w+128) => af[3][4] = 48 VGPRs,
// loaded ONCE via asm outputs (cannot be rematerialized from memory by the
// compiler). Flagless sentinel protocol on hs; consumers validate EVERY bf16
// element (halfword trick), producers store their own 2B element directly
// (sc0 sc1) — no LDS pack, no drain, no flags. Single barrier per step via
// double-buffered partial-sum array.
__global__ __launch_bounds__(512, 2) void gru_scan_kernel(
    const unsigned short* __restrict__ Whh,   // [3072][1024] bf16
    const float* __restrict__ gates,          // [T*B][3072] (= x-gates + b_ih)
    const float* __restrict__ bhh,            // [3072]
    unsigned short* __restrict__ hs) {        // [T+1][B][H] bf16; slice0 = 0
  __shared__ float ghp[2][8][3][16][17];      // [buf][wave][gate][batch][j] (+pad)
  const int tid = threadIdx.x;
  const int g = blockIdx.x;
  const int w = tid >> 6;
  const int l = tid & 63;
  const int lr = l & 15;
  const int lk8 = (l >> 4) * 8;
  const int j0 = g * 16;

  // ---- one-time: W_hh fragments into named registers (asm outputs)
  const unsigned short* ap0 = Whh + (size_t)(j0 + lr) * H_ + w * 128 + lk8;
  const unsigned short* ap1 = ap0 + (size_t)H_ * H_;
  const unsigned short* ap2 = ap1 + (size_t)H_ * H_;
  i32x4 w00, w01, w02, w03, w10, w11, w12, w13, w20, w21, w22, w23;
  asm volatile(
      "global_load_dwordx4 %0,  %12, off\n\t"
      "global_load_dwordx4 %1,  %12, off offset:64\n\t"
      "global_load_dwordx4 %2,  %12, off offset:128\n\t"
      "global_load_dwordx4 %3,  %12, off offset:192\n\t"
      "global_load_dwordx4 %4,  %13, off\n\t"
      "global_load_dwordx4 %5,  %13, off offset:64\n\t"
      "global_load_dwordx4 %6,  %13, off offset:128\n\t"
      "global_load_dwordx4 %7,  %13, off offset:192\n\t"
      "global_load_dwordx4 %8,  %14, off\n\t"
      "global_load_dwordx4 %9,  %14, off offset:64\n\t"
      "global_load_dwordx4 %10, %14, off offset:128\n\t"
      "global_load_dwordx4 %11, %14, off offset:192\n\t"
      "s_waitcnt vmcnt(0)"
      : "=&v"(w00), "=&v"(w01), "=&v"(w02), "=&v"(w03),
        "=&v"(w10), "=&v"(w11), "=&v"(w12), "=&v"(w13),
        "=&v"(w20), "=&v"(w21), "=&v"(w22), "=&v"(w23)
      : "v"(ap0), "v"(ap1), "v"(ap2));
  const bf16x8 af00 = __builtin_bit_cast(bf16x8, w00);
  const bf16x8 af01 = __builtin_bit_cast(bf16x8, w01);
  const bf16x8 af02 = __builtin_bit_cast(bf16x8, w02);
  const bf16x8 af03 = __builtin_bit_cast(bf16x8, w03);
  const bf16x8 af10 = __builtin_bit_cast(bf16x8, w10);
  const bf16x8 af11 = __builtin_bit_cast(bf16x8, w11);
  const bf16x8 af12 = __builtin_bit_cast(bf16x8, w12);
  const bf16x8 af13 = __builtin_bit_cast(bf16x8, w13);
  const bf16x8 af20 = __builtin_bit_cast(bf16x8, w20);
  const bf16x8 af21 = __builtin_bit_cast(bf16x8, w21);
  const bf16x8 af22 = __builtin_bit_cast(bf16x8, w22);
  const bf16x8 af23 = __builtin_bit_cast(bf16x8, w23);

  const int jb = tid & 15;   // j within chunk   (valid for tid < 256)
  const int bb = tid >> 4;   // batch
  const float bhr = bhh[j0 + jb];
  const float bhz = bhh[H_ + j0 + jb];
  const float bhn = bhh[2 * H_ + j0 + jb];
  float hprev = 0.f;

  for (int t = 0; t < T_; ++t) {
    const int buf = t & 1;
    // x-gates for this step (independent of h; issued before the poll)
    float gxr = 0.f, gxz = 0.f, gxn = 0.f;
    if (tid < 256) {
      const size_t grow = ((size_t)t * B_ + bb) * G3_;
      gxr = gates[grow + j0 + jb];
      gxz = gates[grow + H_ + j0 + jb];
      gxn = gates[grow + 2 * H_ + j0 + jb];
    }

    // Poll-load h_t fragments through the coherence point until sentinel-free.
    const unsigned short* hp = hs + (size_t)t * (B_ * H_) +
                               (size_t)lr * H_ + w * 128 + lk8;
    i32x4 u0, u1, u2, u3;
    while (true) {
      asm volatile(
          "global_load_dwordx4 %0, %4, off sc0 sc1\n\t"
          "global_load_dwordx4 %1, %4, off offset:64 sc0 sc1\n\t"
          "global_load_dwordx4 %2, %4, off offset:128 sc0 sc1\n\t"
          "global_load_dwordx4 %3, %4, off offset:192 sc0 sc1\n\t"
          "s_waitcnt vmcnt(0)"
          : "=&v"(u0), "=&v"(u1), "=&v"(u2), "=&v"(u3)
          : "v"(hp)
          : "memory");
      const unsigned bad =
          sentmask(u0[0]) | sentmask(u0[1]) | sentmask(u0[2]) | sentmask(u0[3]) |
          sentmask(u1[0]) | sentmask(u1[1]) | sentmask(u1[2]) | sentmask(u1[3]) |
          sentmask(u2[0]) | sentmask(u2[1]) | sentmask(u2[2]) | sentmask(u2[3]) |
          sentmask(u3[0]) | sentmask(u3[1]) | sentmask(u3[2]) | sentmask(u3[3]);
      if (__ballot(bad == 0) == ~0ull) break;
    }
    const bf16x8 hf0 = __builtin_bit_cast(bf16x8, u0);
    const bf16x8 hf1 = __builtin_bit_cast(bf16x8, u1);
    const bf16x8 hf2 = __builtin_bit_cast(bf16x8, u2);
    const bf16x8 hf3 = __builtin_bit_cast(bf16x8, u3);

    f32x4 C0 = (f32x4){0.f, 0.f, 0.f, 0.f}, C1 = C0, C2 = C0;
    C0 = __builtin_amdgcn_mfma_f32_16x16x32_bf16(af00, hf0, C0, 0, 0, 0);
    C1 = __builtin_amdgcn_mfma_f32_16x16x32_bf16(af10, hf0, C1, 0, 0, 0);
    C2 = __builtin_amdgcn_mfma_f32_16x16x32_bf16(af20, hf0, C2, 0, 0, 0);
    C0 = __builtin_amdgcn_mfma_f32_16x16x32_bf16(af01, hf1, C0, 0, 0, 0);
    C1 = __builtin_amdgcn_mfma_f32_16x16x32_bf16(af11, hf1, C1, 0, 0, 0);
    C2 = __builtin_amdgcn_mfma_f32_16x16x32_bf16(af21, hf1, C2, 0, 0, 0);
    C0 = __builtin_amdgcn_mfma_f32_16x16x32_bf16(af02, hf2, C0, 0, 0, 0);
    C1 = __builtin_amdgcn_mfma_f32_16x16x32_bf16(af12, hf2, C1, 0, 0, 0);
    C2 = __builtin_amdgcn_mfma_f32_16x16x32_bf16(af22, hf2, C2, 0, 0, 0);
    C0 = __builtin_amdgcn_mfma_f32_16x16x32_bf16(af03, hf3, C0, 0, 0, 0);
    C1 = __builtin_amdgcn_mfma_f32_16x16x32_bf16(af13, hf3, C1, 0, 0, 0);
    C2 = __builtin_amdgcn_mfma_f32_16x16x32_bf16(af23, hf3, C2, 0, 0, 0);

    const int rb = (l >> 4) * 4;
#pragma unroll
    for (int e = 0; e < 4; ++e) {
      ghp[buf][w][0][lr][rb + e] = C0[e];
      ghp[buf][w][1][lr][rb + e] = C1[e];
      ghp[buf][w][2][lr][rb + e] = C2[e];
    }
    __syncthreads();   // single barrier per step; buffer parity protects reuse

    if (tid < 256) {
      float sr = bhr, sz = bhz, sn = bhn;
#pragma unroll
      for (int w2 = 0; w2 < 8; ++w2) {
        sr += ghp[buf][w2][0][bb][jb];
        sz += ghp[buf][w2][1][bb][jb];
        sn += ghp[buf][w2][2][bb][jb];
      }
      const float r = 1.f / (1.f + __expf(-(gxr + sr)));
      const float z = 1.f / (1.f + __expf(-(gxz + sz)));
      const float xn = gxn + r * sn;
      const float n = 2.f / (1.f + __expf(-2.f * xn)) - 1.f;
      const float hnew = (1.f - z) * n + z * hprev;   // carry stays fp32
      hprev = hnew;
      unsigned short* sp = hs + ((size_t)(t + 1) * B_ + bb) * H_ + j0 + jb;
      const unsigned hv = (unsigned)f2bf(hnew);
      asm volatile("global_store_short %0, %1, off sc0 sc1"
                   :: "v"(sp), "v"(hv) : "memory");
    }
  }
}

// ---------------------------------------------------------------- launch
extern "C" void kernel_launch(void* const* d_in, const int* in_sizes, int n_in,
                              void* d_out, int out_size, void* d_ws, size_t ws_size,
                              hipStream_t stream) {
  (void)in_sizes; (void)n_in; (void)out_size; (void)ws_size;
  const float* x    = (const float*)d_in[0];
  const float* w3   = (const float*)d_in[1];
  const float* b3   = (const float*)d_in[2];
  const float* w5   = (const float*)d_in[3];
  const float* b5   = (const float*)d_in[4];
  const float* w7   = (const float*)d_in[5];
  const float* b7   = (const float*)d_in[6];
  const float* wih  = (const float*)d_in[7];
  const float* whh  = (const float*)d_in[8];
  const float* bih  = (const float*)d_in[9];
  const float* bhh  = (const float*)d_in[10];
  // d_in[11..14]: attn_* — dead code (softmax over length-1 axis == 1)
  const float* fiw1 = (const float*)d_in[15];
  const float* fib1 = (const float*)d_in[16];
  const float* fiw2 = (const float*)d_in[17];
  const float* fib2 = (const float*)d_in[18];
  const float* lat  = (const float*)d_in[19];

  char* ws = (char*)d_ws;
  size_t off = 0;
  auto alloc = [&](size_t bytes) -> void* {
    void* p = ws + off;
    off += (bytes + 255) & ~(size_t)255;
    return p;
  };
  unsigned short* whh_bf  = (unsigned short*)alloc((size_t)G3_ * H_ * 2);
  unsigned short* wih_bf  = (unsigned short*)alloc((size_t)G3_ * KIN_ * 2);
  unsigned short* latT_bf = (unsigned short*)alloc((size_t)H_ * H_ * 2);
  unsigned short* fiw1_bf = (unsigned short*)alloc((size_t)H_ * H_ * 2);
  unsigned short* fiw2_bf = (unsigned short*)alloc((size_t)H_ * H_ * 2);
  unsigned short* feat_bf = (unsigned short*)alloc((size_t)B_ * T_ * KIN_ * 2);
  float*          gates   = (float*)alloc((size_t)B_ * T_ * G3_ * 4);
  unsigned short* hsbuf   = (unsigned short*)alloc((size_t)(T_ + 1) * B_ * H_ * 2);
  unsigned short* inhib   = (unsigned short*)alloc((size_t)B_ * T_ * H_ * 2);
  unsigned short* y1      = (unsigned short*)alloc((size_t)B_ * T_ * H_ * 2);

  hipMemsetAsync(hsbuf, 0, (size_t)B_ * H_ * 2, stream);   // h0 = 0
  fill_sent_kernel<<<1024, 256, 0, stream>>>(
      (unsigned int*)(hsbuf + (size_t)B_ * H_), T_ * B_ * H_ / 2);

  cvt4_kernel<<<2048, 256, 0, stream>>>(whh, whh_bf, wih, wih_bf,
                                        fiw1, fiw1_bf, fiw2, fiw2_bf);
  transpose_bf16_kernel<<<1024, 256, 0, stream>>>(lat, latT_bf, H_, H_);

  conv_kernel<<<B_ * T_, 256, 0, stream>>>(x, w3, b3, w5, b5, w7, b7, feat_bf);

  {
    dim3 grid(G3_ / 128, (B_ * T_) / 128);
    gemm_kernel<0><<<grid, 256, 0, stream>>>(feat_bf, wih_bf, B_ * T_, G3_, KIN_,
                                             KIN_, KIN_, bih, gates, nullptr);
  }

  gru_scan_kernel<<<64, 512, 0, stream>>>(whh_bf, gates, bhh, hsbuf);

  const unsigned short* hs1 = hsbuf + (size_t)B_ * H_;   // slices 1..T
  {
    dim3 grid(H_ / 128, (B_ * T_) / 128);
    gemm_kernel<1><<<grid, 256, 0, stream>>>(hs1, latT_bf, B_ * T_, H_, H_,
                                             H_, H_, nullptr, nullptr, inhib);
    gemm_kernel<2><<<grid, 256, 0, stream>>>(inhib, fiw1_bf, B_ * T_, H_, H_,
                                             H_, H_, fib1, nullptr, y1);
    gemm_kernel<3><<<grid, 256, 0, stream>>>(y1, fiw2_bf, B_ * T_, H_, H_,
                                             H_, H_, fib2, (float*)d_out, nullptr);
  }

  ones_kernel<<<16, 256, 0, stream>>>((float*)d_out + (size_t)B_ * T_ * H_, B_ * T_);
}